// Round 3
// baseline (559.843 us; speedup 1.0000x reference)
//
#include <hip/hip_runtime.h>

#define IN   128
#define HID  16
#define OUT  64

// K1: xs[i] = x[i]@W_self1 ; xn[i] = x[i]@W_neigh1   (32 nodes per block)
__global__ void k_proj1(const float* __restrict__ x,
                        const float* __restrict__ Ws,
                        const float* __restrict__ Wn,
                        float* __restrict__ xs,
                        float* __restrict__ xn, int n) {
    __shared__ float lw[IN][32];    // 16 KB combined [W_self1 | W_neigh1]
    __shared__ float lx[32][IN];    // 16 KB: 32 node rows
    int tid = threadIdx.x;          // 256 threads
    for (int i = tid; i < IN * 32; i += 256) {
        int k = i >> 5, j = i & 31;
        lw[k][j] = (j < HID) ? Ws[k * HID + j] : Wn[k * HID + (j - 16)];
    }
    int node0 = blockIdx.x * 32;
    const float4* x4 = (const float4*)x;
    for (int i = tid; i < 32 * 32; i += 256) {       // 32 rows x 32 float4
        int r = i >> 5, c4 = i & 31;
        int node = node0 + r;
        float4 v = make_float4(0.f, 0.f, 0.f, 0.f);
        if (node < n) v = x4[(size_t)node * 32 + c4];
        lx[r][c4 * 4 + 0] = v.x; lx[r][c4 * 4 + 1] = v.y;
        lx[r][c4 * 4 + 2] = v.z; lx[r][c4 * 4 + 3] = v.w;
    }
    __syncthreads();
    int j = tid & 31;          // output column 0..31
    int r0 = tid >> 5;         // 0..7 ; rows r0, r0+8, r0+16, r0+24
    float acc0 = 0.f, acc1 = 0.f, acc2 = 0.f, acc3 = 0.f;
    #pragma unroll
    for (int k = 0; k < IN; ++k) {
        float w = lw[k][j];
        acc0 += lx[r0][k] * w;
        acc1 += lx[r0 + 8][k] * w;
        acc2 += lx[r0 + 16][k] * w;
        acc3 += lx[r0 + 24][k] * w;
    }
    float accs[4] = {acc0, acc1, acc2, acc3};
    #pragma unroll
    for (int q = 0; q < 4; ++q) {
        int node = node0 + r0 + q * 8;
        if (node < n) {
            if (j < HID) xs[(size_t)node * HID + j] = accs[q];
            else         xn[(size_t)node * HID + (j - 16)] = accs[q];
        }
    }
}

// ---- CSR build: histogram -> exclusive scan -> place ----

__global__ void k_hist(const int* __restrict__ dst, int* __restrict__ hist, int e) {
    int base = (blockIdx.x * blockDim.x + threadIdx.x) * 4;
    if (base + 3 < e) {
        int4 d4 = *(const int4*)&dst[base];
        atomicAdd(&hist[d4.x], 1);
        atomicAdd(&hist[d4.y], 1);
        atomicAdd(&hist[d4.z], 1);
        atomicAdd(&hist[d4.w], 1);
    } else {
        for (int i = base; i < e; ++i) atomicAdd(&hist[dst[i]], 1);
    }
}

__global__ void k_scan_block(const int* __restrict__ hist,
                             int* __restrict__ rowptr,
                             int* __restrict__ bsum, int n) {
    __shared__ int sm[256];
    int tid = threadIdx.x;
    int i = blockIdx.x * 256 + tid;
    int v = (i < n) ? hist[i] : 0;
    sm[tid] = v;
    __syncthreads();
    for (int off = 1; off < 256; off <<= 1) {
        int t = (tid >= off) ? sm[tid - off] : 0;
        __syncthreads();
        sm[tid] += t;
        __syncthreads();
    }
    if (i < n) rowptr[i] = sm[tid] - v;
    if (tid == 255) bsum[blockIdx.x] = sm[255];
}

__global__ void k_scan_bsum(int* __restrict__ bsum, int nb) {
    __shared__ int sm[256];
    int tid = threadIdx.x;
    int v = (tid < nb) ? bsum[tid] : 0;
    sm[tid] = v;
    __syncthreads();
    for (int off = 1; off < 256; off <<= 1) {
        int t = (tid >= off) ? sm[tid - off] : 0;
        __syncthreads();
        sm[tid] += t;
        __syncthreads();
    }
    if (tid < nb) bsum[tid] = sm[tid] - v;
}

__global__ void k_scan_add(int* __restrict__ rowptr, const int* __restrict__ bsum,
                           int* __restrict__ cursor, int n, int e) {
    int i = blockIdx.x * 256 + threadIdx.x;
    if (i < n) {
        int r = rowptr[i] + bsum[blockIdx.x];
        rowptr[i] = r;
        cursor[i] = r;
    }
    if (i == 0) rowptr[n] = e;
}

// place with 4-edge ILP: 4 independent atomic-return chains per thread
__global__ void k_place(const int* __restrict__ src, const int* __restrict__ dst,
                        int* __restrict__ cursor, int* __restrict__ sorted_src, int e) {
    int base = (blockIdx.x * blockDim.x + threadIdx.x) * 4;
    if (base + 3 < e) {
        int4 s4 = *(const int4*)&src[base];
        int4 d4 = *(const int4*)&dst[base];
        int p0 = atomicAdd(&cursor[d4.x], 1);
        int p1 = atomicAdd(&cursor[d4.y], 1);
        int p2 = atomicAdd(&cursor[d4.z], 1);
        int p3 = atomicAdd(&cursor[d4.w], 1);
        sorted_src[p0] = s4.x;
        sorted_src[p1] = s4.y;
        sorted_src[p2] = s4.z;
        sorted_src[p3] = s4.w;
    } else {
        for (int i = base; i < e; ++i) {
            int pos = atomicAdd(&cursor[dst[i]], 1);
            sorted_src[pos] = src[i];
        }
    }
}

// ---- Layer 1: wave-per-node pull aggregate + finish: h = relu(xs + sum(xn_nb)/deg + b1)
__global__ void k_agg1(const int* __restrict__ rowptr, const int* __restrict__ ssrc,
                       const float* __restrict__ xs, const float* __restrict__ xn,
                       const float* __restrict__ b1,
                       float* __restrict__ h, int n) {
    int wave = threadIdx.x >> 6;
    int lane = threadIdx.x & 63;
    int node = blockIdx.x * 4 + wave;
    if (node >= n) return;
    int s0 = rowptr[node], s1 = rowptr[node + 1];
    int d = lane & 15;
    int g = lane >> 4;            // 4 concurrent edge slots
    float acc = 0.f;
    for (int k = s0 + g; k < s1; k += 4) {
        int s = ssrc[k];
        acc += xn[(size_t)s * HID + d];
    }
    acc += __shfl_xor(acc, 16);
    acc += __shfl_xor(acc, 32);
    if (lane < 16) {
        float dg = fmaxf((float)(s1 - s0), 1.0f);
        float v = xs[(size_t)node * HID + d] + acc / dg + b1[d];
        h[(size_t)node * HID + d] = fmaxf(v, 0.f);
    }
}

// ---- Layer 2 fused: wave-per-node aggregate + output projection
//      out[node] = h[node]@Ws2 + (sum(h_nb)/deg)@Wn2 + b2
__global__ void k_agg2_out(const int* __restrict__ rowptr, const int* __restrict__ ssrc,
                           const float* __restrict__ h,
                           const float* __restrict__ Ws2,
                           const float* __restrict__ Wn2,
                           const float* __restrict__ b2,
                           float* __restrict__ out, int n) {
    __shared__ float lws[HID][OUT];  // 4 KB
    __shared__ float lwn[HID][OUT];  // 4 KB
    int tid = threadIdx.x;
    for (int i = tid; i < HID * OUT; i += 256) {
        lws[i >> 6][i & 63] = Ws2[i];
        lwn[i >> 6][i & 63] = Wn2[i];
    }
    __syncthreads();
    int wave = tid >> 6;
    int lane = tid & 63;
    int d = lane & 15;
    int g = lane >> 4;
    float bias = b2[lane];
    // grid-stride over node groups: amortize the LDS weight load
    for (int nb = blockIdx.x; nb * 4 < n; nb += gridDim.x) {
        int node = nb * 4 + wave;
        if (node < n) {
            int s0 = rowptr[node], s1 = rowptr[node + 1];
            float acc = 0.f;
            for (int k = s0 + g; k < s1; k += 4) {
                int s = ssrc[k];
                acc += h[(size_t)s * HID + d];
            }
            acc += __shfl_xor(acc, 16);
            acc += __shfl_xor(acc, 32);
            float inv = 1.0f / fmaxf((float)(s1 - s0), 1.0f);
            float my_a = acc * inv;                      // a_d (replicated x4)
            float hv = h[(size_t)node * HID + d];        // h_d (replicated x4)
            float accum = bias;
            #pragma unroll
            for (int j = 0; j < HID; ++j) {
                float aj = __shfl(my_a, j);
                float hj = __shfl(hv, j);
                accum += hj * lws[j][lane] + aj * lwn[j][lane];
            }
            out[(size_t)node * OUT + lane] = accum;
        }
    }
}

extern "C" void kernel_launch(void* const* d_in, const int* in_sizes, int n_in,
                              void* d_out, int out_size, void* d_ws, size_t ws_size,
                              hipStream_t stream) {
    const float* x   = (const float*)d_in[0];
    const int*   src = (const int*)d_in[1];
    const int*   dst = (const int*)d_in[2];
    const float* Ws1 = (const float*)d_in[3];
    const float* Wn1 = (const float*)d_in[4];
    const float* b1  = (const float*)d_in[5];
    const float* Ws2 = (const float*)d_in[6];
    const float* Wn2 = (const float*)d_in[7];
    const float* b2  = (const float*)d_in[8];
    float* out = (float*)d_out;

    int n = in_sizes[0] / IN;   // 50000
    int e = in_sizes[1];        // 800000
    int nblk256 = (n + 255) / 256;

    // ws: hist/cursor[n] | bsum[256] | rowptr[n+1] | sorted_src[e] | xs[n*16] | xn[n*16] | h[n*16]
    int* hist_cur   = (int*)d_ws;
    int* bsum       = hist_cur + n;
    int* rowptr     = bsum + 256;
    int* sorted_src = rowptr + (n + 1);
    float* xs = (float*)(sorted_src + e);
    float* xn = xs + (size_t)n * HID;
    float* h  = xn + (size_t)n * HID;

    hipMemsetAsync(hist_cur, 0, (size_t)n * sizeof(int), stream);

    k_proj1<<<(n + 31) / 32, 256, 0, stream>>>(x, Ws1, Wn1, xs, xn, n);

    int e4blk = ((e + 3) / 4 + 255) / 256;
    k_hist<<<e4blk, 256, 0, stream>>>(dst, hist_cur, e);
    k_scan_block<<<nblk256, 256, 0, stream>>>(hist_cur, rowptr, bsum, n);
    k_scan_bsum<<<1, 256, 0, stream>>>(bsum, nblk256);
    k_scan_add<<<nblk256, 256, 0, stream>>>(rowptr, bsum, hist_cur, n, e);
    k_place<<<e4blk, 256, 0, stream>>>(src, dst, hist_cur, sorted_src, e);

    k_agg1<<<(n + 3) / 4, 256, 0, stream>>>(rowptr, sorted_src, xs, xn, b1, h, n);
    k_agg2_out<<<1250, 256, 0, stream>>>(rowptr, sorted_src, h, Ws2, Wn2, b2, out, n);
}

// Round 4
// 184.448 us; speedup vs baseline: 3.0352x; 3.0352x over previous
//
#include <hip/hip_runtime.h>

#define IN   128
#define HID  16
#define OUT  64

// K1: xs[i] = x[i]@W_self1 ; xn[i] = x[i]@W_neigh1
// R1-proven structure: 8 nodes/block, one output element per thread,
// single accumulator (avoids the R3 spill blowup: 4-row unroll -> scratch).
__global__ void k_proj1(const float* __restrict__ x,
                        const float* __restrict__ Ws,
                        const float* __restrict__ Wn,
                        float* __restrict__ xs,
                        float* __restrict__ xn, int n) {
    __shared__ float lw[IN][32];   // 16 KB: combined [W_self1 | W_neigh1]
    __shared__ float lx[8][IN];    // 4 KB: 8 node rows
    int tid = threadIdx.x;  // 256 threads
    for (int i = tid; i < IN * 32; i += 256) {
        int k = i >> 5, j = i & 31;
        lw[k][j] = (j < HID) ? Ws[k * HID + j] : Wn[k * HID + (j - 16)];
    }
    int node0 = blockIdx.x * 8;
    for (int i = tid; i < 8 * IN; i += 256) {
        int r = i >> 7, c = i & 127;
        int node = node0 + r;
        lx[r][c] = (node < n) ? x[(size_t)node * IN + c] : 0.f;
    }
    __syncthreads();
    int r = tid >> 5;     // local node 0..7
    int j = tid & 31;     // output column 0..31
    int node = node0 + r;
    if (node >= n) return;
    float acc = 0.f;
    #pragma unroll
    for (int k = 0; k < IN; ++k) acc += lx[r][k] * lw[k][j];
    if (j < HID) xs[(size_t)node * HID + j] = acc;
    else         xn[(size_t)node * HID + (j - 16)] = acc;
}

// ---- CSR build: histogram -> exclusive scan -> place ----

__global__ void k_hist(const int* __restrict__ dst, int* __restrict__ hist, int e) {
    int base = (blockIdx.x * blockDim.x + threadIdx.x) * 4;
    if (base + 3 < e) {
        int4 d4 = *(const int4*)&dst[base];
        atomicAdd(&hist[d4.x], 1);
        atomicAdd(&hist[d4.y], 1);
        atomicAdd(&hist[d4.z], 1);
        atomicAdd(&hist[d4.w], 1);
    } else {
        for (int i = base; i < e; ++i) atomicAdd(&hist[dst[i]], 1);
    }
}

__global__ void k_scan_block(const int* __restrict__ hist,
                             int* __restrict__ rowptr,
                             int* __restrict__ bsum, int n) {
    __shared__ int sm[256];
    int tid = threadIdx.x;
    int i = blockIdx.x * 256 + tid;
    int v = (i < n) ? hist[i] : 0;
    sm[tid] = v;
    __syncthreads();
    for (int off = 1; off < 256; off <<= 1) {
        int t = (tid >= off) ? sm[tid - off] : 0;
        __syncthreads();
        sm[tid] += t;
        __syncthreads();
    }
    if (i < n) rowptr[i] = sm[tid] - v;
    if (tid == 255) bsum[blockIdx.x] = sm[255];
}

__global__ void k_scan_bsum(int* __restrict__ bsum, int nb) {
    __shared__ int sm[256];
    int tid = threadIdx.x;
    int v = (tid < nb) ? bsum[tid] : 0;
    sm[tid] = v;
    __syncthreads();
    for (int off = 1; off < 256; off <<= 1) {
        int t = (tid >= off) ? sm[tid - off] : 0;
        __syncthreads();
        sm[tid] += t;
        __syncthreads();
    }
    if (tid < nb) bsum[tid] = sm[tid] - v;
}

__global__ void k_scan_add(int* __restrict__ rowptr, const int* __restrict__ bsum,
                           int* __restrict__ cursor, int n, int e) {
    int i = blockIdx.x * 256 + threadIdx.x;
    if (i < n) {
        int r = rowptr[i] + bsum[blockIdx.x];
        rowptr[i] = r;
        cursor[i] = r;
    }
    if (i == 0) rowptr[n] = e;
}

// place with 4-edge ILP: 4 independent atomic-return chains per thread
__global__ void k_place(const int* __restrict__ src, const int* __restrict__ dst,
                        int* __restrict__ cursor, int* __restrict__ sorted_src, int e) {
    int base = (blockIdx.x * blockDim.x + threadIdx.x) * 4;
    if (base + 3 < e) {
        int4 s4 = *(const int4*)&src[base];
        int4 d4 = *(const int4*)&dst[base];
        int p0 = atomicAdd(&cursor[d4.x], 1);
        int p1 = atomicAdd(&cursor[d4.y], 1);
        int p2 = atomicAdd(&cursor[d4.z], 1);
        int p3 = atomicAdd(&cursor[d4.w], 1);
        sorted_src[p0] = s4.x;
        sorted_src[p1] = s4.y;
        sorted_src[p2] = s4.z;
        sorted_src[p3] = s4.w;
    } else {
        for (int i = base; i < e; ++i) {
            int pos = atomicAdd(&cursor[dst[i]], 1);
            sorted_src[pos] = src[i];
        }
    }
}

// ---- Layer 1: wave-per-node pull aggregate + finish: h = relu(xs + sum(xn_nb)/deg + b1)
__global__ void k_agg1(const int* __restrict__ rowptr, const int* __restrict__ ssrc,
                       const float* __restrict__ xs, const float* __restrict__ xn,
                       const float* __restrict__ b1,
                       float* __restrict__ h, int n) {
    int wave = threadIdx.x >> 6;
    int lane = threadIdx.x & 63;
    int node = blockIdx.x * 4 + wave;
    if (node >= n) return;
    int s0 = rowptr[node], s1 = rowptr[node + 1];
    int d = lane & 15;
    int g = lane >> 4;            // 4 concurrent edge slots
    float acc = 0.f;
    for (int k = s0 + g; k < s1; k += 4) {
        int s = ssrc[k];
        acc += xn[(size_t)s * HID + d];
    }
    acc += __shfl_xor(acc, 16);
    acc += __shfl_xor(acc, 32);
    if (lane < 16) {
        float dg = fmaxf((float)(s1 - s0), 1.0f);
        float v = xs[(size_t)node * HID + d] + acc / dg + b1[d];
        h[(size_t)node * HID + d] = fmaxf(v, 0.f);
    }
}

// ---- Layer 2 fused: wave-per-node aggregate + output projection
//      out[node] = h[node]@Ws2 + (sum(h_nb)/deg)@Wn2 + b2
__global__ void k_agg2_out(const int* __restrict__ rowptr, const int* __restrict__ ssrc,
                           const float* __restrict__ h,
                           const float* __restrict__ Ws2,
                           const float* __restrict__ Wn2,
                           const float* __restrict__ b2,
                           float* __restrict__ out, int n) {
    __shared__ float lws[HID][OUT];  // 4 KB
    __shared__ float lwn[HID][OUT];  // 4 KB
    int tid = threadIdx.x;
    for (int i = tid; i < HID * OUT; i += 256) {
        lws[i >> 6][i & 63] = Ws2[i];
        lwn[i >> 6][i & 63] = Wn2[i];
    }
    __syncthreads();
    int wave = tid >> 6;
    int lane = tid & 63;
    int d = lane & 15;
    int g = lane >> 4;
    float bias = b2[lane];
    // grid-stride over node groups: amortize the LDS weight load
    for (int nb = blockIdx.x; nb * 4 < n; nb += gridDim.x) {
        int node = nb * 4 + wave;
        if (node < n) {
            int s0 = rowptr[node], s1 = rowptr[node + 1];
            float acc = 0.f;
            for (int k = s0 + g; k < s1; k += 4) {
                int s = ssrc[k];
                acc += h[(size_t)s * HID + d];
            }
            acc += __shfl_xor(acc, 16);
            acc += __shfl_xor(acc, 32);
            float inv = 1.0f / fmaxf((float)(s1 - s0), 1.0f);
            float my_a = acc * inv;                      // a_d (replicated x4)
            float hv = h[(size_t)node * HID + d];        // h_d (replicated x4)
            float accum = bias;
            #pragma unroll
            for (int j = 0; j < HID; ++j) {
                float aj = __shfl(my_a, j);
                float hj = __shfl(hv, j);
                accum += hj * lws[j][lane] + aj * lwn[j][lane];
            }
            out[(size_t)node * OUT + lane] = accum;
        }
    }
}

extern "C" void kernel_launch(void* const* d_in, const int* in_sizes, int n_in,
                              void* d_out, int out_size, void* d_ws, size_t ws_size,
                              hipStream_t stream) {
    const float* x   = (const float*)d_in[0];
    const int*   src = (const int*)d_in[1];
    const int*   dst = (const int*)d_in[2];
    const float* Ws1 = (const float*)d_in[3];
    const float* Wn1 = (const float*)d_in[4];
    const float* b1  = (const float*)d_in[5];
    const float* Ws2 = (const float*)d_in[6];
    const float* Wn2 = (const float*)d_in[7];
    const float* b2  = (const float*)d_in[8];
    float* out = (float*)d_out;

    int n = in_sizes[0] / IN;   // 50000
    int e = in_sizes[1];        // 800000
    int nblk256 = (n + 255) / 256;

    // ws: hist/cursor[n] | bsum[256] | rowptr[n+1] | sorted_src[e] | xs[n*16] | xn[n*16] | h[n*16]
    int* hist_cur   = (int*)d_ws;
    int* bsum       = hist_cur + n;
    int* rowptr     = bsum + 256;
    int* sorted_src = rowptr + (n + 1);
    float* xs = (float*)(sorted_src + e);
    float* xn = xs + (size_t)n * HID;
    float* h  = xn + (size_t)n * HID;

    hipMemsetAsync(hist_cur, 0, (size_t)n * sizeof(int), stream);

    k_proj1<<<(n + 7) / 8, 256, 0, stream>>>(x, Ws1, Wn1, xs, xn, n);

    int e4blk = ((e + 3) / 4 + 255) / 256;
    k_hist<<<e4blk, 256, 0, stream>>>(dst, hist_cur, e);
    k_scan_block<<<nblk256, 256, 0, stream>>>(hist_cur, rowptr, bsum, n);
    k_scan_bsum<<<1, 256, 0, stream>>>(bsum, nblk256);
    k_scan_add<<<nblk256, 256, 0, stream>>>(rowptr, bsum, hist_cur, n, e);
    k_place<<<e4blk, 256, 0, stream>>>(src, dst, hist_cur, sorted_src, e);

    k_agg1<<<(n + 3) / 4, 256, 0, stream>>>(rowptr, sorted_src, xs, xn, b1, h, n);
    k_agg2_out<<<1250, 256, 0, stream>>>(rowptr, sorted_src, h, Ws2, Wn2, b2, out, n);
}